// Round 1
// 357.620 us; speedup vs baseline: 1.0081x; 1.0081x over previous
//
#include <hip/hip_runtime.h>
#include <cstdint>

typedef __bf16 bf16x8 __attribute__((ext_vector_type(8)));
typedef float f32x4 __attribute__((ext_vector_type(4)));
typedef unsigned short us8 __attribute__((ext_vector_type(8)));

__device__ __forceinline__ unsigned short f2bf(float f) {
  union { float f; uint32_t u; } c; c.f = f;
  uint32_t u = c.u + 0x7FFFu + ((c.u >> 16) & 1u);
  return (unsigned short)(u >> 16);
}

// ---------------------------------------------------------------- convert
__global__ __launch_bounds__(256) void cvt5(
    const float* __restrict__ x1, const float* __restrict__ x2,
    const float* __restrict__ Wq, const float* __restrict__ Wk, const float* __restrict__ Wv,
    unsigned short* __restrict__ xb1, unsigned short* __restrict__ xb2,
    unsigned short* __restrict__ wb) {
  int z = blockIdx.y;
  const float* src; unsigned short* dst; int n4;
  if (z == 0)      { src = x1; dst = xb1;            n4 = 16777216 / 4; }
  else if (z == 1) { src = x2; dst = xb2;            n4 = 16777216 / 4; }
  else if (z == 2) { src = Wq; dst = wb;             n4 = 1048576 / 4; }
  else if (z == 3) { src = Wk; dst = wb + 1048576;   n4 = 1048576 / 4; }
  else             { src = Wv; dst = wb + 2*1048576; n4 = 1048576 / 4; }
  for (int i = blockIdx.x * 256 + threadIdx.x; i < n4; i += gridDim.x * 256) {
    float4 v = ((const float4*)src)[i];
    ushort4 o;
    o.x = f2bf(v.x); o.y = f2bf(v.y); o.z = f2bf(v.z); o.w = f2bf(v.w);
    ((ushort4*)dst)[i] = o;
  }
}

// ---------------------------------------------------------------- GEMM
// R5: 256x256 tile, BK=64, 8 waves (2Mx4N), 8-phase counted-vmcnt schedule
// (T3+T4) + granule XOR swizzle (T2, both-sides: pre-swizzled global source +
// swizzled ds_read) + setprio around MFMA clusters (T5) + XCD swizzle (T1).
// C[m,n] = sum_k A[m,k]*W[n,k] + bias[n];  M=16384, N=K=1024.
//
// LDS 128 KiB: buf0{A 256x64, B 256x64} buf1{...}, bf16 row-major, row=128B.
// Swizzle: logical 16B-granule (row, c16) stored at (row, c16 ^ (row&7)).
// global_load_lds writes linearly (lane*16), so the global src per lane is
// pre-permuted: src granule = (lane&7) ^ (lane>>3)  (row&7 == lane>>3).
//
// Staging stream (4 global_load_lds insts per group, per wave):
//   prologue: A(kt0)->lA0, B(kt0)->lB0, A(kt1)->lA1, vmcnt(4), bar
//   iter t:  P1 stage B(2t+1)->lB1 | P4 stage A(2t+2)->lA0, vmcnt(4)
//            P5 stage B(2t+2)->lB0 | P8 stage A(2t+3)->lA1, vmcnt(4)
// Every region restage is >=1 barrier-phase after its last reader; every
// vmcnt(4) leaves exactly the most recent stage group in flight.
__device__ __forceinline__ void stage_half(const unsigned short* __restrict__ g,
                                           unsigned short* l, int wv, int rl, int cg) {
#pragma unroll
  for (int ld = 0; ld < 2; ++ld) {
    const int chunk = wv * 2 + ld;
    const unsigned short* gp = g + (chunk * 8 + rl) * 1024 + cg * 8;
    unsigned short* lp = l + chunk * 512;
    __builtin_amdgcn_global_load_lds((const __attribute__((address_space(1))) void*)gp,
                                     (__attribute__((address_space(3))) void*)lp,
                                     16, 0, 0);
  }
}

__global__ __launch_bounds__(512) void gemm_qkv(
    const unsigned short* __restrict__ xb1, const unsigned short* __restrict__ xb2,
    const unsigned short* __restrict__ wb,
    const float* __restrict__ bq, const float* __restrict__ bk, const float* __restrict__ bv,
    unsigned short* __restrict__ qkv) {
  __shared__ __attribute__((aligned(16))) unsigned short sm[65536];  // 128 KiB
  unsigned short* lA0 = sm;
  unsigned short* lB0 = sm + 16384;
  unsigned short* lA1 = sm + 32768;
  unsigned short* lB1 = sm + 49152;

  // XCD-aware swizzle: 768 blocks, 96 consecutive per XCD.
  const int id = blockIdx.x;
  const int swz = (id & 7) * 96 + (id >> 3);
  const int z = swz >> 8;            // 0..2  (which GEMM)
  const int rem = swz & 255;
  const int mb = rem >> 2;           // 0..63
  const int nb = rem & 3;            // 0..3
  const int m0 = mb * 256;
  const int n0 = nb * 256;

  const unsigned short* Ag = (z == 0) ? xb1 : xb2;
  const unsigned short* Wg = wb + z * 1048576;
  const float* bias = (z == 0) ? bq : (z == 1 ? bk : bv);
  unsigned short* C = qkv + z * 16777216;

  const int tid = threadIdx.x;
  const int lane = tid & 63;
  const int wv = tid >> 6;           // 0..7
  const int wm = wv >> 2;            // 0..1
  const int wn = wv & 3;             // 0..3
  const int mr = lane & 15;
  const int quad = lane >> 4;

  // staging per-lane constants
  const int rl = lane >> 3;              // row-in-8 of this lane's 16B chunk
  const int cg = (lane & 7) ^ rl;        // pre-swizzled source granule

  // ds_read per-lane constants (swizzled granule offsets, in ushorts)
  const int sg0 = ((quad) ^ (mr & 7)) * 8;        // k-half 0
  const int sg1 = ((4 + quad) ^ (mr & 7)) * 8;    // k-half 1
  const int arow = (wm * 128 + mr) * 64;
  const int brow = (wn * 64 + mr) * 64;

  f32x4 acc[8][4];
#pragma unroll
  for (int i = 0; i < 8; ++i)
#pragma unroll
    for (int j = 0; j < 4; ++j) acc[i][j] = (f32x4){0.f, 0.f, 0.f, 0.f};

  bf16x8 af[4][2], bfr[4][2];

  auto STA = [&](unsigned short* dst, int kt) {
    const unsigned short* g = Ag + m0 * 1024 + kt * 64;
    stage_half(g, dst, wv, rl, cg);
    stage_half(g + 128 * 1024, dst + 8192, wv, rl, cg);
  };
  auto STB = [&](unsigned short* dst, int kt) {
    const unsigned short* g = Wg + n0 * 1024 + kt * 64;
    stage_half(g, dst, wv, rl, cg);
    stage_half(g + 128 * 1024, dst + 8192, wv, rl, cg);
  };
  auto RDA = [&](const unsigned short* lA, int ib) {
#pragma unroll
    for (int i = 0; i < 4; ++i) {
      af[i][0] = *(const bf16x8*)(lA + arow + (ib + i) * 1024 + sg0);
      af[i][1] = *(const bf16x8*)(lA + arow + (ib + i) * 1024 + sg1);
    }
  };
  auto RDB = [&](const unsigned short* lB, int jb) {
#pragma unroll
    for (int j = 0; j < 2; ++j) {
      bfr[jb + j][0] = *(const bf16x8*)(lB + brow + (jb + j) * 1024 + sg0);
      bfr[jb + j][1] = *(const bf16x8*)(lB + brow + (jb + j) * 1024 + sg1);
    }
  };
  auto MF = [&](int ib, int jb) {
#pragma unroll
    for (int i = 0; i < 4; ++i)
#pragma unroll
      for (int j = 0; j < 2; ++j)
#pragma unroll
        for (int h = 0; h < 2; ++h)
          acc[ib + i][jb + j] = __builtin_amdgcn_mfma_f32_16x16x32_bf16(
              af[i][h], bfr[jb + j][h], acc[ib + i][jb + j], 0, 0, 0);
  };

  // ---- prologue
  STA(lA0, 0);
  STB(lB0, 0);
  STA(lA1, 1);
  asm volatile("s_waitcnt vmcnt(4)" ::: "memory");
  __builtin_amdgcn_s_barrier();

#pragma unroll 1
  for (int t = 0; t < 8; ++t) {
    const bool lastt = (t == 7);
    // ---- P1: read buf0 A-lo + B-lo; stage B(2t+1)->lB1 (needed this iter)
    RDA(lA0, 0); RDB(lB0, 0);
    STB(lB1, 2 * t + 1);
    __builtin_amdgcn_s_barrier();
    __builtin_amdgcn_s_setprio(1); MF(0, 0); __builtin_amdgcn_s_setprio(0);
    __builtin_amdgcn_s_barrier();
    // ---- P2: read buf0 B-hi
    RDB(lB0, 2);
    __builtin_amdgcn_s_barrier();
    __builtin_amdgcn_s_setprio(1); MF(0, 2); __builtin_amdgcn_s_setprio(0);
    __builtin_amdgcn_s_barrier();
    // ---- P3: read buf0 A-hi
    RDA(lA0, 4);
    __builtin_amdgcn_s_barrier();
    __builtin_amdgcn_s_setprio(1); MF(4, 0); __builtin_amdgcn_s_setprio(0);
    __builtin_amdgcn_s_barrier();
    // ---- P4: stage A(2t+2)->lA0; W1: buf1's K-tile must be landed
    if (!lastt) STA(lA0, 2 * t + 2);
    __builtin_amdgcn_s_barrier();
    __builtin_amdgcn_s_setprio(1); MF(4, 2); __builtin_amdgcn_s_setprio(0);
    if (lastt) { asm volatile("s_waitcnt vmcnt(0)" ::: "memory"); }
    else       { asm volatile("s_waitcnt vmcnt(4)" ::: "memory"); }
    __builtin_amdgcn_s_barrier();
    // ---- P5: read buf1 A-lo + B-lo; stage B(2t+2)->lB0
    RDA(lA1, 0); RDB(lB1, 0);
    if (!lastt) STB(lB0, 2 * t + 2);
    __builtin_amdgcn_s_barrier();
    __builtin_amdgcn_s_setprio(1); MF(0, 0); __builtin_amdgcn_s_setprio(0);
    __builtin_amdgcn_s_barrier();
    // ---- P6: read buf1 B-hi
    RDB(lB1, 2);
    __builtin_amdgcn_s_barrier();
    __builtin_amdgcn_s_setprio(1); MF(0, 2); __builtin_amdgcn_s_setprio(0);
    __builtin_amdgcn_s_barrier();
    // ---- P7: read buf1 A-hi
    RDA(lA1, 4);
    __builtin_amdgcn_s_barrier();
    __builtin_amdgcn_s_setprio(1); MF(4, 0); __builtin_amdgcn_s_setprio(0);
    __builtin_amdgcn_s_barrier();
    // ---- P8: stage A(2t+3)->lA1; W2: next iter's buf0 K-tile must be landed
    if (!lastt) STA(lA1, 2 * t + 3);
    __builtin_amdgcn_s_barrier();
    __builtin_amdgcn_s_setprio(1); MF(4, 2); __builtin_amdgcn_s_setprio(0);
    if (!lastt) { asm volatile("s_waitcnt vmcnt(4)" ::: "memory"); }
    __builtin_amdgcn_s_barrier();
  }

  // ---- epilogue: C = acc + bias (C/D layout: col = mr, row = quad*4+r)
#pragma unroll
  for (int j = 0; j < 4; ++j) {
    const int col = n0 + wn * 64 + j * 16 + mr;
    const float bb = bias[col];
#pragma unroll
    for (int i = 0; i < 8; ++i) {
      const int rb = m0 + wm * 128 + i * 16 + quad * 4;
#pragma unroll
      for (int r = 0; r < 4; ++r)
        C[(rb + r) * 1024 + col] = f2bf(acc[i][j][r] + bb);
    }
  }
}

// ---------------------------------------------------------------- attention
// R4: XCD-aware flat grid. Blocks {id, id+8, id+16, id+24} are the 4 y-octets
// of one (b,x): same mod-8 class -> same XCD, adjacent in its queue. The Q-slab
// lines (64B each, 16B used per block) are fetched once into that XCD's L2 and
// served 4x -> Q HBM traffic 134MB -> ~34MB.
__global__ __launch_bounds__(256) void attn(const unsigned short* __restrict__ qkv,
                                            float* __restrict__ obuf) {
  const unsigned short* qbuf = qkv;
  const unsigned short* kbuf = qkv + 16777216;
  const unsigned short* vbuf = qkv + 2 * 16777216;
  __shared__ __attribute__((aligned(16))) unsigned short qs[8192];      // [t][m][dy]
  __shared__ __attribute__((aligned(16))) unsigned short ks[4][1024];   // per-wave [t][l]
  __shared__ __attribute__((aligned(16))) unsigned short vs[4][1024];   // per-wave [m][t]
  __shared__ __attribute__((aligned(16))) unsigned short ats[4][1024];  // per-wave [t][l]
  const int id = blockIdx.x;
  const int xcd = id & 7;
  const int pos = id >> 3;
  const int y0 = (pos & 3) * 8;
  const int bx = (pos >> 2) * 8 + xcd;   // 0..511
  const int b = bx >> 5;
  const int x = bx & 31;
  const int lane = threadIdx.x & 63;
  const int wv = threadIdx.x >> 6;
  const int mr = lane & 15, quad = lane >> 4;

#pragma unroll
  for (int it = 0; it < 4; ++it) {
    int c = threadIdx.x + 256 * it;
    int t = c >> 5, m = c & 31;
    const uint4* src = (const uint4*)(qbuf + ((b * 1024 + t * 32 + x) * 1024 + m * 32 + y0));
    ((uint4*)qs)[c] = *src;
  }
  __syncthreads();

  for (int s = 0; s < 2; ++s) {
    int y = y0 + wv * 2 + s;
    int dy = wv * 2 + s;
    const unsigned short* krow = kbuf + ((b * 32 + x) * 32 + y) * 1024;
    const unsigned short* vrow = vbuf + ((b * 32 + x) * 32 + y) * 1024;
    ((uint4*)ks[wv])[lane] = ((const uint4*)krow)[lane];
    ((uint4*)ks[wv])[64 + lane] = ((const uint4*)krow)[64 + lane];
    ((uint4*)vs[wv])[lane] = ((const uint4*)vrow)[lane];
    ((uint4*)vs[wv])[64 + lane] = ((const uint4*)vrow)[64 + lane];

    bf16x8 qa[2], kb[2];
#pragma unroll
    for (int mt = 0; mt < 2; ++mt) {
      us8 tmp;
#pragma unroll
      for (int jj = 0; jj < 8; ++jj)
        tmp[jj] = qs[((quad * 8 + jj) * 32 + mt * 16 + mr) * 8 + dy];
      qa[mt] = __builtin_bit_cast(bf16x8, tmp);
    }
#pragma unroll
    for (int lt = 0; lt < 2; ++lt) {
      us8 tmp;
#pragma unroll
      for (int jj = 0; jj < 8; ++jj)
        tmp[jj] = ks[wv][(quad * 8 + jj) * 32 + lt * 16 + mr];
      kb[lt] = __builtin_bit_cast(bf16x8, tmp);
    }
    f32x4 e[2][2];
#pragma unroll
    for (int mt = 0; mt < 2; ++mt)
#pragma unroll
      for (int lt = 0; lt < 2; ++lt) {
        f32x4 zz = (f32x4){0.f, 0.f, 0.f, 0.f};
        e[mt][lt] = __builtin_amdgcn_mfma_f32_16x16x32_bf16(qa[mt], kb[lt], zz, 0, 0, 0);
      }

#pragma unroll
    for (int mt = 0; mt < 2; ++mt)
#pragma unroll
      for (int r = 0; r < 4; ++r) {
        float v0 = e[mt][0][r], v1 = e[mt][1][r];
        float mx = fmaxf(v0, v1);
#pragma unroll
        for (int off = 1; off < 16; off <<= 1) mx = fmaxf(mx, __shfl_xor(mx, off));
        float p0 = __expf(v0 - mx), p1 = __expf(v1 - mx);
        float sm = p0 + p1;
#pragma unroll
        for (int off = 1; off < 16; off <<= 1) sm += __shfl_xor(sm, off);
        float inv = 1.0f / sm;
        p0 *= inv; p1 *= inv;
        int trow = mt * 16 + quad * 4 + r;
        ats[wv][trow * 32 + mr] = f2bf(p0);
        ats[wv][trow * 32 + 16 + mr] = f2bf(p1);
      }

    bf16x8 va[2], pb[2];
#pragma unroll
    for (int i = 0; i < 2; ++i)
      va[i] = *(const bf16x8*)(&vs[wv][(i * 16 + mr) * 32 + quad * 8]);
#pragma unroll
    for (int lt = 0; lt < 2; ++lt) {
      us8 tmp;
#pragma unroll
      for (int jj = 0; jj < 8; ++jj)
        tmp[jj] = ats[wv][(quad * 8 + jj) * 32 + lt * 16 + mr];
      pb[lt] = __builtin_bit_cast(bf16x8, tmp);
    }
    f32x4 o[2][2];
#pragma unroll
    for (int i = 0; i < 2; ++i)
#pragma unroll
      for (int lt = 0; lt < 2; ++lt) {
        f32x4 zz = (f32x4){0.f, 0.f, 0.f, 0.f};
        o[i][lt] = __builtin_amdgcn_mfma_f32_16x16x32_bf16(va[i], pb[lt], zz, 0, 0, 0);
      }

    float* orow = obuf + ((b * 32 + x) * 32 + y) * 1024;
#pragma unroll
    for (int i = 0; i < 2; ++i)
#pragma unroll
      for (int lt = 0; lt < 2; ++lt)
#pragma unroll
        for (int r = 0; r < 4; ++r)
          orow[(i * 16 + quad * 4 + r) * 32 + lt * 16 + mr] = o[i][lt][r];
  }
}

// ---------------------------------------------------------------- final permute
// out[((b*32+y)*32+l)*1024 + m*32 + x] = obuf[((b*32+x)*32+y)*1024 + m*32 + l]
__global__ __launch_bounds__(256) void transpose2(const float* __restrict__ obuf,
                                                  float* __restrict__ out) {
  __shared__ float t[2][32][33];
  const int y = blockIdx.y, b = blockIdx.z;
  int l = threadIdx.x & 31;
  int g = threadIdx.x >> 5;
#pragma unroll
  for (int mi = 0; mi < 8; ++mi) {
    int m = blockIdx.x * 8 + mi;
    int buf = mi & 1;
    for (int xx = g; xx < 32; xx += 8)
      t[buf][xx][l] = obuf[((b * 32 + xx) * 32 + y) * 1024 + m * 32 + l];
    __syncthreads();
    for (int ll = g; ll < 32; ll += 8)
      out[((b * 32 + y) * 32 + ll) * 1024 + m * 32 + l] = t[buf][l][ll];
  }
}

// ---------------------------------------------------------------- launch
extern "C" void kernel_launch(void* const* d_in, const int* in_sizes, int n_in,
                              void* d_out, int out_size, void* d_ws, size_t ws_size,
                              hipStream_t stream) {
  const float* x1 = (const float*)d_in[0];
  const float* x2 = (const float*)d_in[1];
  const float* Wq = (const float*)d_in[2];
  const float* bq = (const float*)d_in[3];
  const float* Wk = (const float*)d_in[4];
  const float* bk = (const float*)d_in[5];
  const float* Wv = (const float*)d_in[6];
  const float* bv = (const float*)d_in[7];
  float* out = (float*)d_out;

  char* ws = (char*)d_ws;
  unsigned short* xb1 = (unsigned short*)ws;
  unsigned short* xb2 = xb1 + 16777216;
  unsigned short* wb = xb2 + 16777216;
  unsigned short* qkv = wb + 3 * 1048576;
  float* obuf = (float*)ws;  // aliases xb1/xb2 (dead after GEMM)

  cvt5<<<dim3(2048, 5), 256, 0, stream>>>(x1, x2, Wq, Wk, Wv, xb1, xb2, wb);
  gemm_qkv<<<dim3(768), 512, 0, stream>>>(xb1, xb2, wb, bq, bk, bv, qkv);
  attn<<<dim3(2048), 256, 0, stream>>>(qkv, obuf);
  transpose2<<<dim3(4, 32, 16), 256, 0, stream>>>(obuf, out);
}

// Round 2
// 338.677 us; speedup vs baseline: 1.0644x; 1.0559x over previous
//
#include <hip/hip_runtime.h>
#include <cstdint>

typedef __bf16 bf16x8 __attribute__((ext_vector_type(8)));
typedef float f32x4 __attribute__((ext_vector_type(4)));
typedef unsigned short us8 __attribute__((ext_vector_type(8)));

__device__ __forceinline__ unsigned short f2bf(float f) {
  union { float f; uint32_t u; } c; c.f = f;
  uint32_t u = c.u + 0x7FFFu + ((c.u >> 16) & 1u);
  return (unsigned short)(u >> 16);
}

// ---------------------------------------------------------------- convert
__global__ __launch_bounds__(256) void cvt5(
    const float* __restrict__ x1, const float* __restrict__ x2,
    const float* __restrict__ Wq, const float* __restrict__ Wk, const float* __restrict__ Wv,
    unsigned short* __restrict__ xb1, unsigned short* __restrict__ xb2,
    unsigned short* __restrict__ wb) {
  int z = blockIdx.y;
  const float* src; unsigned short* dst; int n4;
  if (z == 0)      { src = x1; dst = xb1;            n4 = 16777216 / 4; }
  else if (z == 1) { src = x2; dst = xb2;            n4 = 16777216 / 4; }
  else if (z == 2) { src = Wq; dst = wb;             n4 = 1048576 / 4; }
  else if (z == 3) { src = Wk; dst = wb + 1048576;   n4 = 1048576 / 4; }
  else             { src = Wv; dst = wb + 2*1048576; n4 = 1048576 / 4; }
  for (int i = blockIdx.x * 256 + threadIdx.x; i < n4; i += gridDim.x * 256) {
    float4 v = ((const float4*)src)[i];
    ushort4 o;
    o.x = f2bf(v.x); o.y = f2bf(v.y); o.z = f2bf(v.z); o.w = f2bf(v.w);
    ((ushort4*)dst)[i] = o;
  }
}

// ---------------------------------------------------------------- GEMM
// R5 loop (unchanged): 256x256 tile, BK=64, 8 waves (2Mx4N), 8-phase
// counted-vmcnt schedule + granule XOR swizzle + setprio + XCD swizzle.
// R6: epilogue rewritten to stage C through LDS (wave-private strips,
// bank-swizzled) -> fully coalesced dwordx4 stores. R1 counters showed
// WRITE_SIZE 180MB vs 96MB ideal from scalar 2B partial-sector stores.
__device__ __forceinline__ void stage_half(const unsigned short* __restrict__ g,
                                           unsigned short* l, int wv, int rl, int cg) {
#pragma unroll
  for (int ld = 0; ld < 2; ++ld) {
    const int chunk = wv * 2 + ld;
    const unsigned short* gp = g + (chunk * 8 + rl) * 1024 + cg * 8;
    unsigned short* lp = l + chunk * 512;
    __builtin_amdgcn_global_load_lds((const __attribute__((address_space(1))) void*)gp,
                                     (__attribute__((address_space(3))) void*)lp,
                                     16, 0, 0);
  }
}

__global__ __launch_bounds__(512) void gemm_qkv(
    const unsigned short* __restrict__ xb1, const unsigned short* __restrict__ xb2,
    const unsigned short* __restrict__ wb,
    const float* __restrict__ bq, const float* __restrict__ bk, const float* __restrict__ bv,
    unsigned short* __restrict__ qkv) {
  __shared__ __attribute__((aligned(16))) unsigned short sm[65536];  // 128 KiB
  unsigned short* lA0 = sm;
  unsigned short* lB0 = sm + 16384;
  unsigned short* lA1 = sm + 32768;
  unsigned short* lB1 = sm + 49152;

  // XCD-aware swizzle: 768 blocks, 96 consecutive per XCD.
  const int id = blockIdx.x;
  const int swz = (id & 7) * 96 + (id >> 3);
  const int z = swz >> 8;            // 0..2  (which GEMM)
  const int rem = swz & 255;
  const int mb = rem >> 2;           // 0..63
  const int nb = rem & 3;            // 0..3
  const int m0 = mb * 256;
  const int n0 = nb * 256;

  const unsigned short* Ag = (z == 0) ? xb1 : xb2;
  const unsigned short* Wg = wb + z * 1048576;
  const float* bias = (z == 0) ? bq : (z == 1 ? bk : bv);
  unsigned short* C = qkv + z * 16777216;

  const int tid = threadIdx.x;
  const int lane = tid & 63;
  const int wv = tid >> 6;           // 0..7
  const int wm = wv >> 2;            // 0..1
  const int wn = wv & 3;             // 0..3
  const int mr = lane & 15;
  const int quad = lane >> 4;

  // staging per-lane constants
  const int rl = lane >> 3;              // row-in-8 of this lane's 16B chunk
  const int cg = (lane & 7) ^ rl;        // pre-swizzled source granule

  // ds_read per-lane constants (swizzled granule offsets, in ushorts)
  const int sg0 = ((quad) ^ (mr & 7)) * 8;        // k-half 0
  const int sg1 = ((4 + quad) ^ (mr & 7)) * 8;    // k-half 1
  const int arow = (wm * 128 + mr) * 64;
  const int brow = (wn * 64 + mr) * 64;

  f32x4 acc[8][4];
#pragma unroll
  for (int i = 0; i < 8; ++i)
#pragma unroll
    for (int j = 0; j < 4; ++j) acc[i][j] = (f32x4){0.f, 0.f, 0.f, 0.f};

  bf16x8 af[4][2], bfr[4][2];

  auto STA = [&](unsigned short* dst, int kt) {
    const unsigned short* g = Ag + m0 * 1024 + kt * 64;
    stage_half(g, dst, wv, rl, cg);
    stage_half(g + 128 * 1024, dst + 8192, wv, rl, cg);
  };
  auto STB = [&](unsigned short* dst, int kt) {
    const unsigned short* g = Wg + n0 * 1024 + kt * 64;
    stage_half(g, dst, wv, rl, cg);
    stage_half(g + 128 * 1024, dst + 8192, wv, rl, cg);
  };
  auto RDA = [&](const unsigned short* lA, int ib) {
#pragma unroll
    for (int i = 0; i < 4; ++i) {
      af[i][0] = *(const bf16x8*)(lA + arow + (ib + i) * 1024 + sg0);
      af[i][1] = *(const bf16x8*)(lA + arow + (ib + i) * 1024 + sg1);
    }
  };
  auto RDB = [&](const unsigned short* lB, int jb) {
#pragma unroll
    for (int j = 0; j < 2; ++j) {
      bfr[jb + j][0] = *(const bf16x8*)(lB + brow + (jb + j) * 1024 + sg0);
      bfr[jb + j][1] = *(const bf16x8*)(lB + brow + (jb + j) * 1024 + sg1);
    }
  };
  auto MF = [&](int ib, int jb) {
#pragma unroll
    for (int i = 0; i < 4; ++i)
#pragma unroll
      for (int j = 0; j < 2; ++j)
#pragma unroll
        for (int h = 0; h < 2; ++h)
          acc[ib + i][jb + j] = __builtin_amdgcn_mfma_f32_16x16x32_bf16(
              af[i][h], bfr[jb + j][h], acc[ib + i][jb + j], 0, 0, 0);
  };

  // ---- prologue
  STA(lA0, 0);
  STB(lB0, 0);
  STA(lA1, 1);
  asm volatile("s_waitcnt vmcnt(4)" ::: "memory");
  __builtin_amdgcn_s_barrier();

#pragma unroll 1
  for (int t = 0; t < 8; ++t) {
    const bool lastt = (t == 7);
    // ---- P1: read buf0 A-lo + B-lo; stage B(2t+1)->lB1 (needed this iter)
    RDA(lA0, 0); RDB(lB0, 0);
    STB(lB1, 2 * t + 1);
    __builtin_amdgcn_s_barrier();
    __builtin_amdgcn_s_setprio(1); MF(0, 0); __builtin_amdgcn_s_setprio(0);
    __builtin_amdgcn_s_barrier();
    // ---- P2: read buf0 B-hi
    RDB(lB0, 2);
    __builtin_amdgcn_s_barrier();
    __builtin_amdgcn_s_setprio(1); MF(0, 2); __builtin_amdgcn_s_setprio(0);
    __builtin_amdgcn_s_barrier();
    // ---- P3: read buf0 A-hi
    RDA(lA0, 4);
    __builtin_amdgcn_s_barrier();
    __builtin_amdgcn_s_setprio(1); MF(4, 0); __builtin_amdgcn_s_setprio(0);
    __builtin_amdgcn_s_barrier();
    // ---- P4: stage A(2t+2)->lA0; W1: buf1's K-tile must be landed
    if (!lastt) STA(lA0, 2 * t + 2);
    __builtin_amdgcn_s_barrier();
    __builtin_amdgcn_s_setprio(1); MF(4, 2); __builtin_amdgcn_s_setprio(0);
    if (lastt) { asm volatile("s_waitcnt vmcnt(0)" ::: "memory"); }
    else       { asm volatile("s_waitcnt vmcnt(4)" ::: "memory"); }
    __builtin_amdgcn_s_barrier();
    // ---- P5: read buf1 A-lo + B-lo; stage B(2t+2)->lB0
    RDA(lA1, 0); RDB(lB1, 0);
    if (!lastt) STB(lB0, 2 * t + 2);
    __builtin_amdgcn_s_barrier();
    __builtin_amdgcn_s_setprio(1); MF(0, 0); __builtin_amdgcn_s_setprio(0);
    __builtin_amdgcn_s_barrier();
    // ---- P6: read buf1 B-hi
    RDB(lB1, 2);
    __builtin_amdgcn_s_barrier();
    __builtin_amdgcn_s_setprio(1); MF(0, 2); __builtin_amdgcn_s_setprio(0);
    __builtin_amdgcn_s_barrier();
    // ---- P7: read buf1 A-hi
    RDA(lA1, 4);
    __builtin_amdgcn_s_barrier();
    __builtin_amdgcn_s_setprio(1); MF(4, 0); __builtin_amdgcn_s_setprio(0);
    __builtin_amdgcn_s_barrier();
    // ---- P8: stage A(2t+3)->lA1; W2: next iter's buf0 K-tile must be landed
    if (!lastt) STA(lA1, 2 * t + 3);
    __builtin_amdgcn_s_barrier();
    __builtin_amdgcn_s_setprio(1); MF(4, 2); __builtin_amdgcn_s_setprio(0);
    if (!lastt) { asm volatile("s_waitcnt vmcnt(4)" ::: "memory"); }
    __builtin_amdgcn_s_barrier();
  }

  // ---- epilogue: stage C-tile through LDS (wave-private 16KB strip) then
  // store coalesced dwordx4 (128B full sectors). Strip layout: [128 r][64 c]
  // bf16, byte ^= ((row>>2)&3)<<5 -> b16 writes hit bits5-6 = j^quad:
  // conflict-free; b128 readback contiguity preserved (XOR above bit 4).
  // No barrier needed: after the loop's final barrier all loop LDS reads are
  // complete (lgkm-waited before their MFMAs), and strips are wave-private.
  {
    unsigned short* strip = sm + wv * 8192;
    float bb[4];
#pragma unroll
    for (int j = 0; j < 4; ++j) bb[j] = bias[n0 + wn * 64 + j * 16 + mr];
#pragma unroll
    for (int i = 0; i < 8; ++i)
#pragma unroll
      for (int j = 0; j < 4; ++j)
#pragma unroll
        for (int r = 0; r < 4; ++r) {
          int row = i * 16 + quad * 4 + r;
          int byteoff = (row * 128 + j * 32 + mr * 2) ^ (((row >> 2) & 3) << 5);
          *(unsigned short*)((char*)strip + byteoff) = f2bf(acc[i][j][r] + bb[j]);
        }
    const int r8 = lane >> 3, c8 = lane & 7;
#pragma unroll
    for (int it = 0; it < 16; ++it) {
      int row = it * 8 + r8;
      int byteoff = (row * 128 + c8 * 16) ^ (((row >> 2) & 3) << 5);
      uint4 vv = *(const uint4*)((const char*)strip + byteoff);
      *(uint4*)(C + (m0 + wm * 128 + row) * 1024 + n0 + wn * 64 + c8 * 8) = vv;
    }
  }
}

// ---------------------------------------------------------------- attention
// R4: XCD-aware flat grid. Blocks {id, id+8, id+16, id+24} are the 4 y-octets
// of one (b,x): same mod-8 class -> same XCD, adjacent in its queue. The Q-slab
// lines (64B each, 16B used per block) are fetched once into that XCD's L2 and
// served 4x -> Q HBM traffic 134MB -> ~34MB.
__global__ __launch_bounds__(256) void attn(const unsigned short* __restrict__ qkv,
                                            float* __restrict__ obuf) {
  const unsigned short* qbuf = qkv;
  const unsigned short* kbuf = qkv + 16777216;
  const unsigned short* vbuf = qkv + 2 * 16777216;
  __shared__ __attribute__((aligned(16))) unsigned short qs[8192];      // [t][m][dy]
  __shared__ __attribute__((aligned(16))) unsigned short ks[4][1024];   // per-wave [t][l]
  __shared__ __attribute__((aligned(16))) unsigned short vs[4][1024];   // per-wave [m][t]
  __shared__ __attribute__((aligned(16))) unsigned short ats[4][1024];  // per-wave [t][l]
  const int id = blockIdx.x;
  const int xcd = id & 7;
  const int pos = id >> 3;
  const int y0 = (pos & 3) * 8;
  const int bx = (pos >> 2) * 8 + xcd;   // 0..511
  const int b = bx >> 5;
  const int x = bx & 31;
  const int lane = threadIdx.x & 63;
  const int wv = threadIdx.x >> 6;
  const int mr = lane & 15, quad = lane >> 4;

#pragma unroll
  for (int it = 0; it < 4; ++it) {
    int c = threadIdx.x + 256 * it;
    int t = c >> 5, m = c & 31;
    const uint4* src = (const uint4*)(qbuf + ((b * 1024 + t * 32 + x) * 1024 + m * 32 + y0));
    ((uint4*)qs)[c] = *src;
  }
  __syncthreads();

  for (int s = 0; s < 2; ++s) {
    int y = y0 + wv * 2 + s;
    int dy = wv * 2 + s;
    const unsigned short* krow = kbuf + ((b * 32 + x) * 32 + y) * 1024;
    const unsigned short* vrow = vbuf + ((b * 32 + x) * 32 + y) * 1024;
    ((uint4*)ks[wv])[lane] = ((const uint4*)krow)[lane];
    ((uint4*)ks[wv])[64 + lane] = ((const uint4*)krow)[64 + lane];
    ((uint4*)vs[wv])[lane] = ((const uint4*)vrow)[lane];
    ((uint4*)vs[wv])[64 + lane] = ((const uint4*)vrow)[64 + lane];

    bf16x8 qa[2], kb[2];
#pragma unroll
    for (int mt = 0; mt < 2; ++mt) {
      us8 tmp;
#pragma unroll
      for (int jj = 0; jj < 8; ++jj)
        tmp[jj] = qs[((quad * 8 + jj) * 32 + mt * 16 + mr) * 8 + dy];
      qa[mt] = __builtin_bit_cast(bf16x8, tmp);
    }
#pragma unroll
    for (int lt = 0; lt < 2; ++lt) {
      us8 tmp;
#pragma unroll
      for (int jj = 0; jj < 8; ++jj)
        tmp[jj] = ks[wv][(quad * 8 + jj) * 32 + lt * 16 + mr];
      kb[lt] = __builtin_bit_cast(bf16x8, tmp);
    }
    f32x4 e[2][2];
#pragma unroll
    for (int mt = 0; mt < 2; ++mt)
#pragma unroll
      for (int lt = 0; lt < 2; ++lt) {
        f32x4 zz = (f32x4){0.f, 0.f, 0.f, 0.f};
        e[mt][lt] = __builtin_amdgcn_mfma_f32_16x16x32_bf16(qa[mt], kb[lt], zz, 0, 0, 0);
      }

#pragma unroll
    for (int mt = 0; mt < 2; ++mt)
#pragma unroll
      for (int r = 0; r < 4; ++r) {
        float v0 = e[mt][0][r], v1 = e[mt][1][r];
        float mx = fmaxf(v0, v1);
#pragma unroll
        for (int off = 1; off < 16; off <<= 1) mx = fmaxf(mx, __shfl_xor(mx, off));
        float p0 = __expf(v0 - mx), p1 = __expf(v1 - mx);
        float sm = p0 + p1;
#pragma unroll
        for (int off = 1; off < 16; off <<= 1) sm += __shfl_xor(sm, off);
        float inv = 1.0f / sm;
        p0 *= inv; p1 *= inv;
        int trow = mt * 16 + quad * 4 + r;
        ats[wv][trow * 32 + mr] = f2bf(p0);
        ats[wv][trow * 32 + 16 + mr] = f2bf(p1);
      }

    bf16x8 va[2], pb[2];
#pragma unroll
    for (int i = 0; i < 2; ++i)
      va[i] = *(const bf16x8*)(&vs[wv][(i * 16 + mr) * 32 + quad * 8]);
#pragma unroll
    for (int lt = 0; lt < 2; ++lt) {
      us8 tmp;
#pragma unroll
      for (int jj = 0; jj < 8; ++jj)
        tmp[jj] = ats[wv][(quad * 8 + jj) * 32 + lt * 16 + mr];
      pb[lt] = __builtin_bit_cast(bf16x8, tmp);
    }
    f32x4 o[2][2];
#pragma unroll
    for (int i = 0; i < 2; ++i)
#pragma unroll
      for (int lt = 0; lt < 2; ++lt) {
        f32x4 zz = (f32x4){0.f, 0.f, 0.f, 0.f};
        o[i][lt] = __builtin_amdgcn_mfma_f32_16x16x32_bf16(va[i], pb[lt], zz, 0, 0, 0);
      }

    float* orow = obuf + ((b * 32 + x) * 32 + y) * 1024;
#pragma unroll
    for (int i = 0; i < 2; ++i)
#pragma unroll
      for (int lt = 0; lt < 2; ++lt)
#pragma unroll
        for (int r = 0; r < 4; ++r)
          orow[(i * 16 + quad * 4 + r) * 32 + lt * 16 + mr] = o[i][lt][r];
  }
}

// ---------------------------------------------------------------- final permute
// out[((b*32+y)*32+l)*1024 + m*32 + x] = obuf[((b*32+x)*32+y)*1024 + m*32 + l]
// R6: float4 both sides via padded LDS tile (was 4B/lane scalar).
__global__ __launch_bounds__(256) void transpose2(const float* __restrict__ obuf,
                                                  float* __restrict__ out) {
  __shared__ float t[2][32][36];  // pad 36: keeps float4 stores 16B-aligned
  const int y = blockIdx.y, b = blockIdx.z;
  const int r = threadIdx.x >> 3;   // 0..31
  const int cg = threadIdx.x & 7;   // 0..7
  for (int mi = 0; mi < 8; ++mi) {
    int m = blockIdx.x * 8 + mi;
    int buf = mi & 1;
    float4 v = *(const float4*)(obuf + ((b * 32 + r) * 32 + y) * 1024 + m * 32 + cg * 4);
    *(float4*)&t[buf][r][cg * 4] = v;
    __syncthreads();
    float4 w;
    w.x = t[buf][cg * 4 + 0][r];
    w.y = t[buf][cg * 4 + 1][r];
    w.z = t[buf][cg * 4 + 2][r];
    w.w = t[buf][cg * 4 + 3][r];
    *(float4*)(out + ((b * 32 + y) * 32 + r) * 1024 + m * 32 + cg * 4) = w;
  }
}

// ---------------------------------------------------------------- launch
extern "C" void kernel_launch(void* const* d_in, const int* in_sizes, int n_in,
                              void* d_out, int out_size, void* d_ws, size_t ws_size,
                              hipStream_t stream) {
  const float* x1 = (const float*)d_in[0];
  const float* x2 = (const float*)d_in[1];
  const float* Wq = (const float*)d_in[2];
  const float* bq = (const float*)d_in[3];
  const float* Wk = (const float*)d_in[4];
  const float* bk = (const float*)d_in[5];
  const float* Wv = (const float*)d_in[6];
  const float* bv = (const float*)d_in[7];
  float* out = (float*)d_out;

  char* ws = (char*)d_ws;
  unsigned short* xb1 = (unsigned short*)ws;
  unsigned short* xb2 = xb1 + 16777216;
  unsigned short* wb = xb2 + 16777216;
  unsigned short* qkv = wb + 3 * 1048576;
  float* obuf = (float*)ws;  // aliases xb1/xb2 (dead after GEMM)

  cvt5<<<dim3(2048, 5), 256, 0, stream>>>(x1, x2, Wq, Wk, Wv, xb1, xb2, wb);
  gemm_qkv<<<dim3(768), 512, 0, stream>>>(xb1, xb2, wb, bq, bk, bv, qkv);
  attn<<<dim3(2048), 256, 0, stream>>>(qkv, obuf);
  transpose2<<<dim3(4, 32, 16), 256, 0, stream>>>(obuf, out);
}

// Round 3
// 330.182 us; speedup vs baseline: 1.0918x; 1.0257x over previous
//
#include <hip/hip_runtime.h>
#include <cstdint>

typedef __bf16 bf16x8 __attribute__((ext_vector_type(8)));
typedef float f32x4 __attribute__((ext_vector_type(4)));
typedef unsigned short us8 __attribute__((ext_vector_type(8)));

__device__ __forceinline__ unsigned short f2bf(float f) {
  union { float f; uint32_t u; } c; c.f = f;
  uint32_t u = c.u + 0x7FFFu + ((c.u >> 16) & 1u);
  return (unsigned short)(u >> 16);
}
__device__ __forceinline__ float bf2f(unsigned short u) {
  union { uint32_t u; float f; } c; c.u = ((uint32_t)u) << 16; return c.f;
}

// ---------------------------------------------------------------- convert
__global__ __launch_bounds__(256) void cvt5(
    const float* __restrict__ x1, const float* __restrict__ x2,
    const float* __restrict__ Wq, const float* __restrict__ Wk, const float* __restrict__ Wv,
    unsigned short* __restrict__ xb1, unsigned short* __restrict__ xb2,
    unsigned short* __restrict__ wb) {
  int z = blockIdx.y;
  const float* src; unsigned short* dst; int n4;
  if (z == 0)      { src = x1; dst = xb1;            n4 = 16777216 / 4; }
  else if (z == 1) { src = x2; dst = xb2;            n4 = 16777216 / 4; }
  else if (z == 2) { src = Wq; dst = wb;             n4 = 1048576 / 4; }
  else if (z == 3) { src = Wk; dst = wb + 1048576;   n4 = 1048576 / 4; }
  else             { src = Wv; dst = wb + 2*1048576; n4 = 1048576 / 4; }
  for (int i = blockIdx.x * 256 + threadIdx.x; i < n4; i += gridDim.x * 256) {
    float4 v = ((const float4*)src)[i];
    ushort4 o;
    o.x = f2bf(v.x); o.y = f2bf(v.y); o.z = f2bf(v.z); o.w = f2bf(v.w);
    ((ushort4*)dst)[i] = o;
  }
}

// ---------------------------------------------------------------- GEMM
// R5 loop (frozen): 256x256 tile, BK=64, 8 waves (2Mx4N), 8-phase
// counted-vmcnt schedule + granule XOR swizzle + setprio + XCD swizzle.
// R6 epilogue (frozen): LDS-bounced coalesced dwordx4 C stores
// (WRITE_SIZE verified at the 96 MiB ideal).
__device__ __forceinline__ void stage_half(const unsigned short* __restrict__ g,
                                           unsigned short* l, int wv, int rl, int cg) {
#pragma unroll
  for (int ld = 0; ld < 2; ++ld) {
    const int chunk = wv * 2 + ld;
    const unsigned short* gp = g + (chunk * 8 + rl) * 1024 + cg * 8;
    unsigned short* lp = l + chunk * 512;
    __builtin_amdgcn_global_load_lds((const __attribute__((address_space(1))) void*)gp,
                                     (__attribute__((address_space(3))) void*)lp,
                                     16, 0, 0);
  }
}

__global__ __launch_bounds__(512) void gemm_qkv(
    const unsigned short* __restrict__ xb1, const unsigned short* __restrict__ xb2,
    const unsigned short* __restrict__ wb,
    const float* __restrict__ bq, const float* __restrict__ bk, const float* __restrict__ bv,
    unsigned short* __restrict__ qkv) {
  __shared__ __attribute__((aligned(16))) unsigned short sm[65536];  // 128 KiB
  unsigned short* lA0 = sm;
  unsigned short* lB0 = sm + 16384;
  unsigned short* lA1 = sm + 32768;
  unsigned short* lB1 = sm + 49152;

  // XCD-aware swizzle: 768 blocks, 96 consecutive per XCD.
  const int id = blockIdx.x;
  const int swz = (id & 7) * 96 + (id >> 3);
  const int z = swz >> 8;            // 0..2  (which GEMM)
  const int rem = swz & 255;
  const int mb = rem >> 2;           // 0..63
  const int nb = rem & 3;            // 0..3
  const int m0 = mb * 256;
  const int n0 = nb * 256;

  const unsigned short* Ag = (z == 0) ? xb1 : xb2;
  const unsigned short* Wg = wb + z * 1048576;
  const float* bias = (z == 0) ? bq : (z == 1 ? bk : bv);
  unsigned short* C = qkv + z * 16777216;

  const int tid = threadIdx.x;
  const int lane = tid & 63;
  const int wv = tid >> 6;           // 0..7
  const int wm = wv >> 2;            // 0..1
  const int wn = wv & 3;             // 0..3
  const int mr = lane & 15;
  const int quad = lane >> 4;

  // staging per-lane constants
  const int rl = lane >> 3;              // row-in-8 of this lane's 16B chunk
  const int cg = (lane & 7) ^ rl;        // pre-swizzled source granule

  // ds_read per-lane constants (swizzled granule offsets, in ushorts)
  const int sg0 = ((quad) ^ (mr & 7)) * 8;        // k-half 0
  const int sg1 = ((4 + quad) ^ (mr & 7)) * 8;    // k-half 1
  const int arow = (wm * 128 + mr) * 64;
  const int brow = (wn * 64 + mr) * 64;

  f32x4 acc[8][4];
#pragma unroll
  for (int i = 0; i < 8; ++i)
#pragma unroll
    for (int j = 0; j < 4; ++j) acc[i][j] = (f32x4){0.f, 0.f, 0.f, 0.f};

  bf16x8 af[4][2], bfr[4][2];

  auto STA = [&](unsigned short* dst, int kt) {
    const unsigned short* g = Ag + m0 * 1024 + kt * 64;
    stage_half(g, dst, wv, rl, cg);
    stage_half(g + 128 * 1024, dst + 8192, wv, rl, cg);
  };
  auto STB = [&](unsigned short* dst, int kt) {
    const unsigned short* g = Wg + n0 * 1024 + kt * 64;
    stage_half(g, dst, wv, rl, cg);
    stage_half(g + 128 * 1024, dst + 8192, wv, rl, cg);
  };
  auto RDA = [&](const unsigned short* lA, int ib) {
#pragma unroll
    for (int i = 0; i < 4; ++i) {
      af[i][0] = *(const bf16x8*)(lA + arow + (ib + i) * 1024 + sg0);
      af[i][1] = *(const bf16x8*)(lA + arow + (ib + i) * 1024 + sg1);
    }
  };
  auto RDB = [&](const unsigned short* lB, int jb) {
#pragma unroll
    for (int j = 0; j < 2; ++j) {
      bfr[jb + j][0] = *(const bf16x8*)(lB + brow + (jb + j) * 1024 + sg0);
      bfr[jb + j][1] = *(const bf16x8*)(lB + brow + (jb + j) * 1024 + sg1);
    }
  };
  auto MF = [&](int ib, int jb) {
#pragma unroll
    for (int i = 0; i < 4; ++i)
#pragma unroll
      for (int j = 0; j < 2; ++j)
#pragma unroll
        for (int h = 0; h < 2; ++h)
          acc[ib + i][jb + j] = __builtin_amdgcn_mfma_f32_16x16x32_bf16(
              af[i][h], bfr[jb + j][h], acc[ib + i][jb + j], 0, 0, 0);
  };

  // ---- prologue
  STA(lA0, 0);
  STB(lB0, 0);
  STA(lA1, 1);
  asm volatile("s_waitcnt vmcnt(4)" ::: "memory");
  __builtin_amdgcn_s_barrier();

#pragma unroll 1
  for (int t = 0; t < 8; ++t) {
    const bool lastt = (t == 7);
    // ---- P1: read buf0 A-lo + B-lo; stage B(2t+1)->lB1 (needed this iter)
    RDA(lA0, 0); RDB(lB0, 0);
    STB(lB1, 2 * t + 1);
    __builtin_amdgcn_s_barrier();
    __builtin_amdgcn_s_setprio(1); MF(0, 0); __builtin_amdgcn_s_setprio(0);
    __builtin_amdgcn_s_barrier();
    // ---- P2: read buf0 B-hi
    RDB(lB0, 2);
    __builtin_amdgcn_s_barrier();
    __builtin_amdgcn_s_setprio(1); MF(0, 2); __builtin_amdgcn_s_setprio(0);
    __builtin_amdgcn_s_barrier();
    // ---- P3: read buf0 A-hi
    RDA(lA0, 4);
    __builtin_amdgcn_s_barrier();
    __builtin_amdgcn_s_setprio(1); MF(4, 0); __builtin_amdgcn_s_setprio(0);
    __builtin_amdgcn_s_barrier();
    // ---- P4: stage A(2t+2)->lA0; W1: buf1's K-tile must be landed
    if (!lastt) STA(lA0, 2 * t + 2);
    __builtin_amdgcn_s_barrier();
    __builtin_amdgcn_s_setprio(1); MF(4, 2); __builtin_amdgcn_s_setprio(0);
    if (lastt) { asm volatile("s_waitcnt vmcnt(0)" ::: "memory"); }
    else       { asm volatile("s_waitcnt vmcnt(4)" ::: "memory"); }
    __builtin_amdgcn_s_barrier();
    // ---- P5: read buf1 A-lo + B-lo; stage B(2t+2)->lB0
    RDA(lA1, 0); RDB(lB1, 0);
    if (!lastt) STB(lB0, 2 * t + 2);
    __builtin_amdgcn_s_barrier();
    __builtin_amdgcn_s_setprio(1); MF(0, 0); __builtin_amdgcn_s_setprio(0);
    __builtin_amdgcn_s_barrier();
    // ---- P6: read buf1 B-hi
    RDB(lB1, 2);
    __builtin_amdgcn_s_barrier();
    __builtin_amdgcn_s_setprio(1); MF(0, 2); __builtin_amdgcn_s_setprio(0);
    __builtin_amdgcn_s_barrier();
    // ---- P7: read buf1 A-hi
    RDA(lA1, 4);
    __builtin_amdgcn_s_barrier();
    __builtin_amdgcn_s_setprio(1); MF(4, 0); __builtin_amdgcn_s_setprio(0);
    __builtin_amdgcn_s_barrier();
    // ---- P8: stage A(2t+3)->lA1; W2: next iter's buf0 K-tile must be landed
    if (!lastt) STA(lA1, 2 * t + 3);
    __builtin_amdgcn_s_barrier();
    __builtin_amdgcn_s_setprio(1); MF(4, 2); __builtin_amdgcn_s_setprio(0);
    if (!lastt) { asm volatile("s_waitcnt vmcnt(4)" ::: "memory"); }
    __builtin_amdgcn_s_barrier();
  }

  // ---- epilogue: stage C-tile through LDS (wave-private 16KB strip) then
  // store coalesced dwordx4 (128B full sectors).
  {
    unsigned short* strip = sm + wv * 8192;
    float bb[4];
#pragma unroll
    for (int j = 0; j < 4; ++j) bb[j] = bias[n0 + wn * 64 + j * 16 + mr];
#pragma unroll
    for (int i = 0; i < 8; ++i)
#pragma unroll
      for (int j = 0; j < 4; ++j)
#pragma unroll
        for (int r = 0; r < 4; ++r) {
          int row = i * 16 + quad * 4 + r;
          int byteoff = (row * 128 + j * 32 + mr * 2) ^ (((row >> 2) & 3) << 5);
          *(unsigned short*)((char*)strip + byteoff) = f2bf(acc[i][j][r] + bb[j]);
        }
    const int r8 = lane >> 3, c8 = lane & 7;
#pragma unroll
    for (int it = 0; it < 16; ++it) {
      int row = it * 8 + r8;
      int byteoff = (row * 128 + c8 * 16) ^ (((row >> 2) & 3) << 5);
      uint4 vv = *(const uint4*)((const char*)strip + byteoff);
      *(uint4*)(C + (m0 + wm * 128 + row) * 1024 + n0 + wn * 64 + c8 * 8) = vv;
    }
  }
}

// ---------------------------------------------------------------- attention
// R4: XCD-aware flat grid (Q-slab L2 reuse across the 4 y-octet blocks).
// R7: (a) P written TRANSPOSED to LDS (atsT[l][t], stride 40 bf16) so the PV
// B-fragment is 2x ds_read_b128 instead of 16 scalar ds_read_u16 gathers;
// (b) output staged to LDS bf16 tile then stored as 2 fully-coalesced 1KB
// uint4 rows of a bf16 obuf (was 16 partial-sector scalar f32 stores;
// obuf traffic halved).
__global__ __launch_bounds__(256) void attn(const unsigned short* __restrict__ qkv,
                                            unsigned short* __restrict__ obuf) {
  const unsigned short* qbuf = qkv;
  const unsigned short* kbuf = qkv + 16777216;
  const unsigned short* vbuf = qkv + 2 * 16777216;
  __shared__ __attribute__((aligned(16))) unsigned short qs[8192];      // [t][m][dy]
  __shared__ __attribute__((aligned(16))) unsigned short ks[4][1024];   // per-wave [t][l]
  __shared__ __attribute__((aligned(16))) unsigned short vs[4][1024];   // per-wave [m][t]
  __shared__ __attribute__((aligned(16))) unsigned short ats[4][1280];  // per-wave P^T [l][t] stride 40
  __shared__ __attribute__((aligned(16))) unsigned short obb[4][1024];  // per-wave o bf16 [m][l]
  const int id = blockIdx.x;
  const int xcd = id & 7;
  const int pos = id >> 3;
  const int y0 = (pos & 3) * 8;
  const int bx = (pos >> 2) * 8 + xcd;   // 0..511
  const int b = bx >> 5;
  const int x = bx & 31;
  const int lane = threadIdx.x & 63;
  const int wv = threadIdx.x >> 6;
  const int mr = lane & 15, quad = lane >> 4;

#pragma unroll
  for (int it = 0; it < 4; ++it) {
    int c = threadIdx.x + 256 * it;
    int t = c >> 5, m = c & 31;
    const uint4* src = (const uint4*)(qbuf + ((b * 1024 + t * 32 + x) * 1024 + m * 32 + y0));
    ((uint4*)qs)[c] = *src;
  }
  __syncthreads();

  for (int s = 0; s < 2; ++s) {
    int y = y0 + wv * 2 + s;
    int dy = wv * 2 + s;
    const unsigned short* krow = kbuf + ((b * 32 + x) * 32 + y) * 1024;
    const unsigned short* vrow = vbuf + ((b * 32 + x) * 32 + y) * 1024;
    ((uint4*)ks[wv])[lane] = ((const uint4*)krow)[lane];
    ((uint4*)ks[wv])[64 + lane] = ((const uint4*)krow)[64 + lane];
    ((uint4*)vs[wv])[lane] = ((const uint4*)vrow)[lane];
    ((uint4*)vs[wv])[64 + lane] = ((const uint4*)vrow)[64 + lane];

    bf16x8 qa[2], kb[2];
#pragma unroll
    for (int mt = 0; mt < 2; ++mt) {
      us8 tmp;
#pragma unroll
      for (int jj = 0; jj < 8; ++jj)
        tmp[jj] = qs[((quad * 8 + jj) * 32 + mt * 16 + mr) * 8 + dy];
      qa[mt] = __builtin_bit_cast(bf16x8, tmp);
    }
#pragma unroll
    for (int lt = 0; lt < 2; ++lt) {
      us8 tmp;
#pragma unroll
      for (int jj = 0; jj < 8; ++jj)
        tmp[jj] = ks[wv][(quad * 8 + jj) * 32 + lt * 16 + mr];
      kb[lt] = __builtin_bit_cast(bf16x8, tmp);
    }
    f32x4 e[2][2];
#pragma unroll
    for (int mt = 0; mt < 2; ++mt)
#pragma unroll
      for (int lt = 0; lt < 2; ++lt) {
        f32x4 zz = (f32x4){0.f, 0.f, 0.f, 0.f};
        e[mt][lt] = __builtin_amdgcn_mfma_f32_16x16x32_bf16(qa[mt], kb[lt], zz, 0, 0, 0);
      }

#pragma unroll
    for (int mt = 0; mt < 2; ++mt)
#pragma unroll
      for (int r = 0; r < 4; ++r) {
        float v0 = e[mt][0][r], v1 = e[mt][1][r];
        float mx = fmaxf(v0, v1);
#pragma unroll
        for (int off = 1; off < 16; off <<= 1) mx = fmaxf(mx, __shfl_xor(mx, off));
        float p0 = __expf(v0 - mx), p1 = __expf(v1 - mx);
        float sm = p0 + p1;
#pragma unroll
        for (int off = 1; off < 16; off <<= 1) sm += __shfl_xor(sm, off);
        float inv = 1.0f / sm;
        p0 *= inv; p1 *= inv;
        int trow = mt * 16 + quad * 4 + r;
        // P^T: atsT[l][t], row stride 40 (pad keeps b128 16B-aligned, spreads banks)
        ats[wv][mr * 40 + trow] = f2bf(p0);
        ats[wv][(16 + mr) * 40 + trow] = f2bf(p1);
      }

    bf16x8 va[2], pb[2];
#pragma unroll
    for (int i = 0; i < 2; ++i)
      va[i] = *(const bf16x8*)(&vs[wv][(i * 16 + mr) * 32 + quad * 8]);
#pragma unroll
    for (int lt = 0; lt < 2; ++lt)
      pb[lt] = *(const bf16x8*)(&ats[wv][(lt * 16 + mr) * 40 + quad * 8]);
    f32x4 o[2][2];
#pragma unroll
    for (int i = 0; i < 2; ++i)
#pragma unroll
      for (int lt = 0; lt < 2; ++lt) {
        f32x4 zz = (f32x4){0.f, 0.f, 0.f, 0.f};
        o[i][lt] = __builtin_amdgcn_mfma_f32_16x16x32_bf16(va[i], pb[lt], zz, 0, 0, 0);
      }

    // stage o -> LDS bf16 [m][l], then 2 coalesced 1KB row stores
#pragma unroll
    for (int i = 0; i < 2; ++i)
#pragma unroll
      for (int lt = 0; lt < 2; ++lt)
#pragma unroll
        for (int r = 0; r < 4; ++r)
          obb[wv][(i * 16 + quad * 4 + r) * 32 + lt * 16 + mr] = f2bf(o[i][lt][r]);
    unsigned short* orow = obuf + ((b * 32 + x) * 32 + y) * 1024;
#pragma unroll
    for (int h = 0; h < 2; ++h)
      *(uint4*)(orow + h * 512 + lane * 8) = *(const uint4*)(&obb[wv][h * 512 + lane * 8]);
  }
}

// ---------------------------------------------------------------- final permute
// out[((b*32+y)*32+l)*1024 + m*32 + x] = bf2f(obuf[((b*32+x)*32+y)*1024 + m*32 + l])
// R7: bf16 source (halved read traffic), cvt to f32 in LDS, float4 out.
__global__ __launch_bounds__(256) void transpose2(const unsigned short* __restrict__ obuf,
                                                  float* __restrict__ out) {
  __shared__ float t[2][32][36];  // pad 36: keeps float4 stores 16B-aligned
  const int y = blockIdx.y, b = blockIdx.z;
  const int r = threadIdx.x >> 3;   // 0..31
  const int cg = threadIdx.x & 7;   // 0..7
  for (int mi = 0; mi < 8; ++mi) {
    int m = blockIdx.x * 8 + mi;
    int buf = mi & 1;
    ushort4 v = *(const ushort4*)(obuf + ((b * 32 + r) * 32 + y) * 1024 + m * 32 + cg * 4);
    t[buf][r][cg * 4 + 0] = bf2f(v.x);
    t[buf][r][cg * 4 + 1] = bf2f(v.y);
    t[buf][r][cg * 4 + 2] = bf2f(v.z);
    t[buf][r][cg * 4 + 3] = bf2f(v.w);
    __syncthreads();
    float4 w;
    w.x = t[buf][cg * 4 + 0][r];
    w.y = t[buf][cg * 4 + 1][r];
    w.z = t[buf][cg * 4 + 2][r];
    w.w = t[buf][cg * 4 + 3][r];
    *(float4*)(out + ((b * 32 + y) * 32 + r) * 1024 + m * 32 + cg * 4) = w;
  }
}

// ---------------------------------------------------------------- launch
extern "C" void kernel_launch(void* const* d_in, const int* in_sizes, int n_in,
                              void* d_out, int out_size, void* d_ws, size_t ws_size,
                              hipStream_t stream) {
  const float* x1 = (const float*)d_in[0];
  const float* x2 = (const float*)d_in[1];
  const float* Wq = (const float*)d_in[2];
  const float* bq = (const float*)d_in[3];
  const float* Wk = (const float*)d_in[4];
  const float* bk = (const float*)d_in[5];
  const float* Wv = (const float*)d_in[6];
  const float* bv = (const float*)d_in[7];
  float* out = (float*)d_out;

  char* ws = (char*)d_ws;
  unsigned short* xb1 = (unsigned short*)ws;
  unsigned short* xb2 = xb1 + 16777216;
  unsigned short* wb = xb2 + 16777216;
  unsigned short* qkv = wb + 3 * 1048576;
  unsigned short* obuf16 = (unsigned short*)ws;  // aliases xb1 (dead after GEMM)

  cvt5<<<dim3(2048, 5), 256, 0, stream>>>(x1, x2, Wq, Wk, Wv, xb1, xb2, wb);
  gemm_qkv<<<dim3(768), 512, 0, stream>>>(xb1, xb2, wb, bq, bk, bv, qkv);
  attn<<<dim3(2048), 256, 0, stream>>>(qkv, obuf16);
  transpose2<<<dim3(4, 32, 16), 256, 0, stream>>>(obuf16, out);
}

// Round 4
// 324.877 us; speedup vs baseline: 1.1096x; 1.0163x over previous
//
#include <hip/hip_runtime.h>
#include <cstdint>

typedef __bf16 bf16x8 __attribute__((ext_vector_type(8)));
typedef float f32x4 __attribute__((ext_vector_type(4)));
typedef unsigned short us8 __attribute__((ext_vector_type(8)));

__device__ __forceinline__ unsigned short f2bf(float f) {
  union { float f; uint32_t u; } c; c.f = f;
  uint32_t u = c.u + 0x7FFFu + ((c.u >> 16) & 1u);
  return (unsigned short)(u >> 16);
}
__device__ __forceinline__ float bf2f(unsigned short u) {
  union { uint32_t u; float f; } c; c.u = ((uint32_t)u) << 16; return c.f;
}

// ---------------------------------------------------------------- convert
__global__ __launch_bounds__(256) void cvt5(
    const float* __restrict__ x1, const float* __restrict__ x2,
    const float* __restrict__ Wq, const float* __restrict__ Wk, const float* __restrict__ Wv,
    unsigned short* __restrict__ xb1, unsigned short* __restrict__ xb2,
    unsigned short* __restrict__ wb) {
  int z = blockIdx.y;
  const float* src; unsigned short* dst; int n4;
  if (z == 0)      { src = x1; dst = xb1;            n4 = 16777216 / 4; }
  else if (z == 1) { src = x2; dst = xb2;            n4 = 16777216 / 4; }
  else if (z == 2) { src = Wq; dst = wb;             n4 = 1048576 / 4; }
  else if (z == 3) { src = Wk; dst = wb + 1048576;   n4 = 1048576 / 4; }
  else             { src = Wv; dst = wb + 2*1048576; n4 = 1048576 / 4; }
  for (int i = blockIdx.x * 256 + threadIdx.x; i < n4; i += gridDim.x * 256) {
    float4 v = ((const float4*)src)[i];
    ushort4 o;
    o.x = f2bf(v.x); o.y = f2bf(v.y); o.z = f2bf(v.z); o.w = f2bf(v.w);
    ((ushort4*)dst)[i] = o;
  }
}

// ---------------------------------------------------------------- GEMM
// R5 loop (frozen): 256x256 tile, BK=64, 8 waves (2Mx4N), 8-phase
// counted-vmcnt schedule + granule XOR swizzle + setprio + XCD swizzle.
// R6 epilogue (frozen): LDS-bounced coalesced dwordx4 C stores.
// R8: for z==1 (K), the B-operand ROW SELECTION is permuted so the output is
// K stored transposed-within-row: K'[b,i,j][l*32+c] = K[b,i,j][c*32+l].
// Output column col' holds original col = (col'&31)*32 + (col'>>5); staged
// W-row for tile row rt is (rt&31)*32 + nb*8 + (rt>>5). MFMA/A-staging/
// epilogue layout unchanged; bias indexed through the inverse permutation.
// This makes attn's K fragment a direct coalesced global load (no LDS).
__global__ __launch_bounds__(512) void gemm_qkv(
    const unsigned short* __restrict__ xb1, const unsigned short* __restrict__ xb2,
    const unsigned short* __restrict__ wb,
    const float* __restrict__ bq, const float* __restrict__ bk, const float* __restrict__ bv,
    unsigned short* __restrict__ qkv) {
  __shared__ __attribute__((aligned(16))) unsigned short sm[65536];  // 128 KiB
  unsigned short* lA0 = sm;
  unsigned short* lB0 = sm + 16384;
  unsigned short* lA1 = sm + 32768;
  unsigned short* lB1 = sm + 49152;

  // XCD-aware swizzle: 768 blocks, 96 consecutive per XCD.
  const int id = blockIdx.x;
  const int swz = (id & 7) * 96 + (id >> 3);
  const int z = swz >> 8;            // 0..2  (which GEMM)
  const int rem = swz & 255;
  const int mb = rem >> 2;           // 0..63
  const int nb = rem & 3;            // 0..3
  const int m0 = mb * 256;
  const int n0 = nb * 256;

  const unsigned short* Ag = (z == 0) ? xb1 : xb2;
  const unsigned short* Wg = wb + z * 1048576;
  const float* bias = (z == 0) ? bq : (z == 1 ? bk : bv);
  unsigned short* C = qkv + z * 16777216;

  const int tid = threadIdx.x;
  const int lane = tid & 63;
  const int wv = tid >> 6;           // 0..7
  const int wm = wv >> 2;            // 0..1
  const int wn = wv & 3;             // 0..3
  const int mr = lane & 15;
  const int quad = lane >> 4;

  // staging per-lane constants
  const int rl = lane >> 3;              // row-in-8 of this lane's 16B chunk
  const int cg = (lane & 7) ^ rl;        // pre-swizzled source granule

  // per-lane staging pointers (4 chunks each for A and B) + wave-uniform LDS offs
  const unsigned short* aptr[4];
  const unsigned short* bptr[4];
  int ldoff[4];
#pragma unroll
  for (int half = 0; half < 2; ++half)
#pragma unroll
    for (int ld = 0; ld < 2; ++ld) {
      const int q2 = half * 2 + ld;
      const int chunk = wv * 2 + ld;
      const int rt = half * 128 + chunk * 8 + rl;
      aptr[q2] = Ag + (m0 + rt) * 1024 + cg * 8;
      const int wrow = (z == 1) ? ((rt & 31) * 32 + nb * 8 + (rt >> 5)) : (n0 + rt);
      bptr[q2] = Wg + wrow * 1024 + cg * 8;
      ldoff[q2] = half * 8192 + chunk * 512;
    }

  // ds_read per-lane constants (swizzled granule offsets, in ushorts)
  const int sg0 = ((quad) ^ (mr & 7)) * 8;        // k-half 0
  const int sg1 = ((4 + quad) ^ (mr & 7)) * 8;    // k-half 1
  const int arow = (wm * 128 + mr) * 64;
  const int brow = (wn * 64 + mr) * 64;

  f32x4 acc[8][4];
#pragma unroll
  for (int i = 0; i < 8; ++i)
#pragma unroll
    for (int j = 0; j < 4; ++j) acc[i][j] = (f32x4){0.f, 0.f, 0.f, 0.f};

  bf16x8 af[4][2], bfr[4][2];

  auto STA = [&](unsigned short* dst, int kt) {
#pragma unroll
    for (int q2 = 0; q2 < 4; ++q2)
      __builtin_amdgcn_global_load_lds(
          (const __attribute__((address_space(1))) void*)(aptr[q2] + kt * 64),
          (__attribute__((address_space(3))) void*)(dst + ldoff[q2]), 16, 0, 0);
  };
  auto STB = [&](unsigned short* dst, int kt) {
#pragma unroll
    for (int q2 = 0; q2 < 4; ++q2)
      __builtin_amdgcn_global_load_lds(
          (const __attribute__((address_space(1))) void*)(bptr[q2] + kt * 64),
          (__attribute__((address_space(3))) void*)(dst + ldoff[q2]), 16, 0, 0);
  };
  auto RDA = [&](const unsigned short* lA, int ib) {
#pragma unroll
    for (int i = 0; i < 4; ++i) {
      af[i][0] = *(const bf16x8*)(lA + arow + (ib + i) * 1024 + sg0);
      af[i][1] = *(const bf16x8*)(lA + arow + (ib + i) * 1024 + sg1);
    }
  };
  auto RDB = [&](const unsigned short* lB, int jb) {
#pragma unroll
    for (int j = 0; j < 2; ++j) {
      bfr[jb + j][0] = *(const bf16x8*)(lB + brow + (jb + j) * 1024 + sg0);
      bfr[jb + j][1] = *(const bf16x8*)(lB + brow + (jb + j) * 1024 + sg1);
    }
  };
  auto MF = [&](int ib, int jb) {
#pragma unroll
    for (int i = 0; i < 4; ++i)
#pragma unroll
      for (int j = 0; j < 2; ++j)
#pragma unroll
        for (int h = 0; h < 2; ++h)
          acc[ib + i][jb + j] = __builtin_amdgcn_mfma_f32_16x16x32_bf16(
              af[i][h], bfr[jb + j][h], acc[ib + i][jb + j], 0, 0, 0);
  };

  // ---- prologue
  STA(lA0, 0);
  STB(lB0, 0);
  STA(lA1, 1);
  asm volatile("s_waitcnt vmcnt(4)" ::: "memory");
  __builtin_amdgcn_s_barrier();

#pragma unroll 1
  for (int t = 0; t < 8; ++t) {
    const bool lastt = (t == 7);
    // ---- P1: read buf0 A-lo + B-lo; stage B(2t+1)->lB1 (needed this iter)
    RDA(lA0, 0); RDB(lB0, 0);
    STB(lB1, 2 * t + 1);
    __builtin_amdgcn_s_barrier();
    __builtin_amdgcn_s_setprio(1); MF(0, 0); __builtin_amdgcn_s_setprio(0);
    __builtin_amdgcn_s_barrier();
    // ---- P2: read buf0 B-hi
    RDB(lB0, 2);
    __builtin_amdgcn_s_barrier();
    __builtin_amdgcn_s_setprio(1); MF(0, 2); __builtin_amdgcn_s_setprio(0);
    __builtin_amdgcn_s_barrier();
    // ---- P3: read buf0 A-hi
    RDA(lA0, 4);
    __builtin_amdgcn_s_barrier();
    __builtin_amdgcn_s_setprio(1); MF(4, 0); __builtin_amdgcn_s_setprio(0);
    __builtin_amdgcn_s_barrier();
    // ---- P4: stage A(2t+2)->lA0; W1: buf1's K-tile must be landed
    if (!lastt) STA(lA0, 2 * t + 2);
    __builtin_amdgcn_s_barrier();
    __builtin_amdgcn_s_setprio(1); MF(4, 2); __builtin_amdgcn_s_setprio(0);
    if (lastt) { asm volatile("s_waitcnt vmcnt(0)" ::: "memory"); }
    else       { asm volatile("s_waitcnt vmcnt(4)" ::: "memory"); }
    __builtin_amdgcn_s_barrier();
    // ---- P5: read buf1 A-lo + B-lo; stage B(2t+2)->lB0
    RDA(lA1, 0); RDB(lB1, 0);
    if (!lastt) STB(lB0, 2 * t + 2);
    __builtin_amdgcn_s_barrier();
    __builtin_amdgcn_s_setprio(1); MF(0, 0); __builtin_amdgcn_s_setprio(0);
    __builtin_amdgcn_s_barrier();
    // ---- P6: read buf1 B-hi
    RDB(lB1, 2);
    __builtin_amdgcn_s_barrier();
    __builtin_amdgcn_s_setprio(1); MF(0, 2); __builtin_amdgcn_s_setprio(0);
    __builtin_amdgcn_s_barrier();
    // ---- P7: read buf1 A-hi
    RDA(lA1, 4);
    __builtin_amdgcn_s_barrier();
    __builtin_amdgcn_s_setprio(1); MF(4, 0); __builtin_amdgcn_s_setprio(0);
    __builtin_amdgcn_s_barrier();
    // ---- P8: stage A(2t+3)->lA1; W2: next iter's buf0 K-tile must be landed
    if (!lastt) STA(lA1, 2 * t + 3);
    __builtin_amdgcn_s_barrier();
    __builtin_amdgcn_s_setprio(1); MF(4, 2); __builtin_amdgcn_s_setprio(0);
    if (!lastt) { asm volatile("s_waitcnt vmcnt(4)" ::: "memory"); }
    __builtin_amdgcn_s_barrier();
  }

  // ---- epilogue: stage C-tile through LDS (wave-private 16KB strip) then
  // store coalesced dwordx4 (128B full sectors). Bias for z==1 goes through
  // the inverse column permutation.
  {
    unsigned short* strip = sm + wv * 8192;
    float bb[4];
#pragma unroll
    for (int j = 0; j < 4; ++j) {
      int colp = n0 + wn * 64 + j * 16 + mr;
      int col = (z == 1) ? ((colp & 31) * 32 + (colp >> 5)) : colp;
      bb[j] = bias[col];
    }
#pragma unroll
    for (int i = 0; i < 8; ++i)
#pragma unroll
      for (int j = 0; j < 4; ++j)
#pragma unroll
        for (int r = 0; r < 4; ++r) {
          int row = i * 16 + quad * 4 + r;
          int byteoff = (row * 128 + j * 32 + mr * 2) ^ (((row >> 2) & 3) << 5);
          *(unsigned short*)((char*)strip + byteoff) = f2bf(acc[i][j][r] + bb[j]);
        }
    const int r8 = lane >> 3, c8 = lane & 7;
#pragma unroll
    for (int it = 0; it < 16; ++it) {
      int row = it * 8 + r8;
      int byteoff = (row * 128 + c8 * 16) ^ (((row >> 2) & 3) << 5);
      uint4 vv = *(const uint4*)((const char*)strip + byteoff);
      *(uint4*)(C + (m0 + wm * 128 + row) * 1024 + n0 + wn * 64 + c8 * 8) = vv;
    }
  }
}

// ---------------------------------------------------------------- attention
// R8: K (pre-transposed by GEMM) and V fragments are DIRECT global uint4
// loads, prefetched for both s-iterations at block start (HBM latency hides
// under Q staging + QK^T). Q staged TRANSPOSED: qs[dy][m][c] with 2-bit
// c-granule XOR swizzle (g' = (c>>3) ^ ((m>>1)&3)); qa = 2x ds_read_b128
// (2-way, free) instead of 16 scalar gathers. ks/vs LDS deleted (50->34KB,
// 4 blocks/CU). P^T (R7) and coalesced bf16 output (R7) kept.
__global__ __launch_bounds__(256) void attn(const unsigned short* __restrict__ qkv,
                                            unsigned short* __restrict__ obuf) {
  const unsigned short* qbuf = qkv;
  const unsigned short* kbuf = qkv + 16777216;      // K' [b,i,j][l*32+c]
  const unsigned short* vbuf = qkv + 2 * 16777216;  // V  [b,i,j][m*32+t]
  __shared__ __attribute__((aligned(16))) unsigned short qs[8192];      // [dy][m][c] swz
  __shared__ __attribute__((aligned(16))) unsigned short ats[4][1280];  // per-wave P^T [l][t] stride 40
  __shared__ __attribute__((aligned(16))) unsigned short obb[4][1024];  // per-wave o bf16 [m][l]
  const int id = blockIdx.x;
  const int xcd = id & 7;
  const int pos = id >> 3;
  const int y0 = (pos & 3) * 8;
  const int bx = (pos >> 2) * 8 + xcd;   // 0..511
  const int b = bx >> 5;
  const int x = bx & 31;
  const int lane = threadIdx.x & 63;
  const int wv = threadIdx.x >> 6;
  const int mr = lane & 15, quad = lane >> 4;

  // ---- prefetch K/V fragments for both s (direct, fully coalesced) ----
  uint4 kpre[2][2], vpre[2][2];
#pragma unroll
  for (int s = 0; s < 2; ++s) {
    int y = y0 + wv * 2 + s;
    const unsigned short* krow = kbuf + ((b * 32 + x) * 32 + y) * 1024;
    const unsigned short* vrow = vbuf + ((b * 32 + x) * 32 + y) * 1024;
#pragma unroll
    for (int lt = 0; lt < 2; ++lt)
      kpre[s][lt] = *(const uint4*)(krow + (lt * 16 + mr) * 32 + quad * 8);
#pragma unroll
    for (int i = 0; i < 2; ++i)
      vpre[s][i] = *(const uint4*)(vrow + (i * 16 + mr) * 32 + quad * 8);
  }

  // ---- Q stage: transpose to qs[dy][m][swizzled c] ----
#pragma unroll
  for (int it = 0; it < 4; ++it) {
    int cl = threadIdx.x + 256 * it;
    int t = cl >> 5, m = cl & 31;
    uint4 v = *(const uint4*)(qbuf + ((b * 1024 + t * 32 + x) * 1024 + m * 32 + y0));
    us8 e = __builtin_bit_cast(us8, v);
    int g = ((t >> 3) ^ ((m >> 1) & 3)) * 8 + (t & 7);
#pragma unroll
    for (int dy = 0; dy < 8; ++dy)
      qs[dy * 1024 + m * 32 + g] = e[dy];
  }
  __syncthreads();

  for (int s = 0; s < 2; ++s) {
    int y = y0 + wv * 2 + s;
    int dy = wv * 2 + s;

    bf16x8 qa[2], kb[2];
#pragma unroll
    for (int mt = 0; mt < 2; ++mt)
      qa[mt] = *(const bf16x8*)(qs + dy * 1024 + (mt * 16 + mr) * 32 +
                                (quad ^ ((mr >> 1) & 3)) * 8);
    kb[0] = __builtin_bit_cast(bf16x8, kpre[s][0]);
    kb[1] = __builtin_bit_cast(bf16x8, kpre[s][1]);

    f32x4 e[2][2];
#pragma unroll
    for (int mt = 0; mt < 2; ++mt)
#pragma unroll
      for (int lt = 0; lt < 2; ++lt) {
        f32x4 zz = (f32x4){0.f, 0.f, 0.f, 0.f};
        e[mt][lt] = __builtin_amdgcn_mfma_f32_16x16x32_bf16(qa[mt], kb[lt], zz, 0, 0, 0);
      }

#pragma unroll
    for (int mt = 0; mt < 2; ++mt)
#pragma unroll
      for (int r = 0; r < 4; ++r) {
        float v0 = e[mt][0][r], v1 = e[mt][1][r];
        float mx = fmaxf(v0, v1);
#pragma unroll
        for (int off = 1; off < 16; off <<= 1) mx = fmaxf(mx, __shfl_xor(mx, off));
        float p0 = __expf(v0 - mx), p1 = __expf(v1 - mx);
        float sm = p0 + p1;
#pragma unroll
        for (int off = 1; off < 16; off <<= 1) sm += __shfl_xor(sm, off);
        float inv = 1.0f / sm;
        p0 *= inv; p1 *= inv;
        int trow = mt * 16 + quad * 4 + r;
        ats[wv][mr * 40 + trow] = f2bf(p0);
        ats[wv][(16 + mr) * 40 + trow] = f2bf(p1);
      }

    bf16x8 va[2], pb[2];
    va[0] = __builtin_bit_cast(bf16x8, vpre[s][0]);
    va[1] = __builtin_bit_cast(bf16x8, vpre[s][1]);
#pragma unroll
    for (int lt = 0; lt < 2; ++lt)
      pb[lt] = *(const bf16x8*)(&ats[wv][(lt * 16 + mr) * 40 + quad * 8]);
    f32x4 o[2][2];
#pragma unroll
    for (int i = 0; i < 2; ++i)
#pragma unroll
      for (int lt = 0; lt < 2; ++lt) {
        f32x4 zz = (f32x4){0.f, 0.f, 0.f, 0.f};
        o[i][lt] = __builtin_amdgcn_mfma_f32_16x16x32_bf16(va[i], pb[lt], zz, 0, 0, 0);
      }

    // stage o -> LDS bf16 [m][l], then 2 coalesced 1KB row stores
#pragma unroll
    for (int i = 0; i < 2; ++i)
#pragma unroll
      for (int lt = 0; lt < 2; ++lt)
#pragma unroll
        for (int r = 0; r < 4; ++r)
          obb[wv][(i * 16 + quad * 4 + r) * 32 + lt * 16 + mr] = f2bf(o[i][lt][r]);
    unsigned short* orow = obuf + ((b * 32 + x) * 32 + y) * 1024;
#pragma unroll
    for (int h = 0; h < 2; ++h)
      *(uint4*)(orow + h * 512 + lane * 8) = *(const uint4*)(&obb[wv][h * 512 + lane * 8]);
  }
}

// ---------------------------------------------------------------- final permute
// out[((b*32+y)*32+l)*1024 + m*32 + x] = bf2f(obuf[((b*32+x)*32+y)*1024 + m*32 + l])
__global__ __launch_bounds__(256) void transpose2(const unsigned short* __restrict__ obuf,
                                                  float* __restrict__ out) {
  __shared__ float t[2][32][36];  // pad 36: keeps float4 stores 16B-aligned
  const int y = blockIdx.y, b = blockIdx.z;
  const int r = threadIdx.x >> 3;   // 0..31
  const int cg = threadIdx.x & 7;   // 0..7
  for (int mi = 0; mi < 8; ++mi) {
    int m = blockIdx.x * 8 + mi;
    int buf = mi & 1;
    ushort4 v = *(const ushort4*)(obuf + ((b * 32 + r) * 32 + y) * 1024 + m * 32 + cg * 4);
    t[buf][r][cg * 4 + 0] = bf2f(v.x);
    t[buf][r][cg * 4 + 1] = bf2f(v.y);
    t[buf][r][cg * 4 + 2] = bf2f(v.z);
    t[buf][r][cg * 4 + 3] = bf2f(v.w);
    __syncthreads();
    float4 w;
    w.x = t[buf][cg * 4 + 0][r];
    w.y = t[buf][cg * 4 + 1][r];
    w.z = t[buf][cg * 4 + 2][r];
    w.w = t[buf][cg * 4 + 3][r];
    *(float4*)(out + ((b * 32 + y) * 32 + r) * 1024 + m * 32 + cg * 4) = w;
  }
}

// ---------------------------------------------------------------- launch
extern "C" void kernel_launch(void* const* d_in, const int* in_sizes, int n_in,
                              void* d_out, int out_size, void* d_ws, size_t ws_size,
                              hipStream_t stream) {
  const float* x1 = (const float*)d_in[0];
  const float* x2 = (const float*)d_in[1];
  const float* Wq = (const float*)d_in[2];
  const float* bq = (const float*)d_in[3];
  const float* Wk = (const float*)d_in[4];
  const float* bk = (const float*)d_in[5];
  const float* Wv = (const float*)d_in[6];
  const float* bv = (const float*)d_in[7];
  float* out = (float*)d_out;

  char* ws = (char*)d_ws;
  unsigned short* xb1 = (unsigned short*)ws;
  unsigned short* xb2 = xb1 + 16777216;
  unsigned short* wb = xb2 + 16777216;
  unsigned short* qkv = wb + 3 * 1048576;
  unsigned short* obuf16 = (unsigned short*)ws;  // aliases xb1 (dead after GEMM)

  cvt5<<<dim3(2048, 5), 256, 0, stream>>>(x1, x2, Wq, Wk, Wv, xb1, xb2, wb);
  gemm_qkv<<<dim3(768), 512, 0, stream>>>(xb1, xb2, wb, bq, bk, bv, qkv);
  attn<<<dim3(2048), 256, 0, stream>>>(qkv, obuf16);
  transpose2<<<dim3(4, 32, 16), 256, 0, stream>>>(obuf16, out);
}